// Round 3
// baseline (210.120 us; speedup 1.0000x reference)
//
#include <hip/hip_runtime.h>
#include <math.h>

#define BLOCKS  2048
#define THREADS 256

// Native clang vector type: works with __builtin_nontemporal_store
// (HIP's float4 class type does not).
typedef float floatx4 __attribute__((ext_vector_type(4)));

// ---------------------------------------------------------------------------
// Fused pointwise transform (everything between the two normalizations).
//   theta = -pi + 2*pi*sigmoid(x)     (exact closed form of the linspace lerp)
//   ds    = 3 * |tanh(x)|             (exact closed form of the linspace lerp)
//   y     = x * exp(ds*sin(theta)) + ds*cos(theta)
// Trans-op-minimal version: ~5 transcendental ops, ~14 VALU ops.
//   w = e^{-|x|} (one v_exp, no overflow);  sigmoid & tanh derived from w.
//   sin(theta) = v_sin(sg - 0.5) since v_sin takes REVOLUTIONS: theta/2pi = sg-0.5.
// ---------------------------------------------------------------------------
__device__ __forceinline__ float transform(float d, float mean1, float scale1) {
    float x  = (d - mean1) * scale1;              // scale1 = iscale / std1
    float ax = fabsf(x);
    float w  = __expf(-ax);                       // e^{-|x|}  in (0,1]
    float r  = __builtin_amdgcn_rcpf(1.0f + w);   // sigma(|x|) = 1/(1+w)
    float sg = (x >= 0.0f) ? r : (1.0f - r);      // sigmoid(x)
    float u  = w * w;                             // e^{-2|x|}
    float th = (1.0f - u) * __builtin_amdgcn_rcpf(1.0f + u);  // |tanh(x)| in [0,1]
    float ds = 3.0f * th;
    float rev = sg - 0.5f;                        // theta / (2*pi), in (-0.5, 0.5)
    float sn = __builtin_amdgcn_sinf(rev);        // sin(theta)  (hw: revolutions)
    float cs = __builtin_amdgcn_cosf(rev);        // cos(theta)
    return fmaf(x, __expf(ds * sn), ds * cs);     // x*exp(dy) + dx
}

// Block-level {sum, sumsq} reduction in double. Result valid in thread 0.
__device__ __forceinline__ void block_reduce2(double& s, double& ss) {
    for (int o = 32; o > 0; o >>= 1) {
        s  += __shfl_down(s,  o);
        ss += __shfl_down(ss, o);
    }
    __shared__ double ls[4], lss[4];
    const int wave = threadIdx.x >> 6;
    const int lane = threadIdx.x & 63;
    if (lane == 0) { ls[wave] = s; lss[wave] = ss; }
    __syncthreads();
    if (threadIdx.x == 0) {
        s = ls[0]; ss = lss[0];
        #pragma unroll
        for (int w = 1; w < THREADS / 64; ++w) { s += ls[w]; ss += lss[w]; }
    }
}

// Last-block-finalize: per-block partials + device-scope counter; the final
// block to arrive reduces all partials (fixed order -> deterministic).
__device__ __forceinline__ bool publish_and_check_last(
        double s, double ss, double* __restrict__ part, unsigned* __restrict__ counter) {
    __shared__ bool amLast;
    if (threadIdx.x == 0) {
        part[2 * blockIdx.x]     = s;
        part[2 * blockIdx.x + 1] = ss;
        __threadfence();                           // release partials device-wide
        unsigned prev = atomicAdd(counter, 1u);    // device-scope by default
        amLast = (prev == gridDim.x - 1);
    }
    __syncthreads();
    if (amLast) __threadfence();                   // acquire
    return amLast;
}

// Pass 1: {sum, sumsq} of raw data; last block writes params[0..1].
//   params[0] = mean1, params[1] = iscale/std1 (ddof=1)
__global__ __launch_bounds__(THREADS) void k_stats1(
        const floatx4* __restrict__ in, double* __restrict__ part,
        float* __restrict__ params, const float* __restrict__ iscale,
        unsigned* __restrict__ counter, int n4, int n) {
    double s = 0.0, ss = 0.0;
    const int stride = gridDim.x * blockDim.x;
    for (int i = blockIdx.x * blockDim.x + threadIdx.x; i < n4; i += stride) {
        floatx4 v = in[i];
        s  += ((double)v.x + (double)v.y) + ((double)v.z + (double)v.w);
        ss += ((double)v.x * v.x + (double)v.y * v.y)
            + ((double)v.z * v.z + (double)v.w * v.w);
    }
    block_reduce2(s, ss);
    if (publish_and_check_last(s, ss, part, counter)) {
        double ts = 0.0, tss = 0.0;
        for (int i = threadIdx.x; i < (int)gridDim.x; i += blockDim.x) {
            ts += part[2 * i]; tss += part[2 * i + 1];
        }
        block_reduce2(ts, tss);
        if (threadIdx.x == 0) {
            double dn   = (double)n;
            double mean = ts / dn;
            double var  = (tss - ts * ts / dn) / (dn - 1.0);
            params[0] = (float)mean;
            params[1] = (float)((1.0 / sqrt(var)) * (double)iscale[0]);
            __threadfence();
        }
    }
}

// Pass 2: {sum, sumsq} of transformed y (recomputed); last block writes
//   params[2] = oscale/std2, params[3] = -mean2 * params[2]
__global__ __launch_bounds__(THREADS) void k_stats2(
        const floatx4* __restrict__ in, double* __restrict__ part,
        float* __restrict__ params, const float* __restrict__ oscale,
        unsigned* __restrict__ counter, int n4, int n) {
    const float mean1  = params[0];
    const float scale1 = params[1];
    double s = 0.0, ss = 0.0;
    const int stride = gridDim.x * blockDim.x;
    for (int i = blockIdx.x * blockDim.x + threadIdx.x; i < n4; i += stride) {
        floatx4 v = in[i];
        float y0 = transform(v.x, mean1, scale1);
        float y1 = transform(v.y, mean1, scale1);
        float y2 = transform(v.z, mean1, scale1);
        float y3 = transform(v.w, mean1, scale1);
        s  += ((double)y0 + (double)y1) + ((double)y2 + (double)y3);
        ss += ((double)y0 * y0 + (double)y1 * y1)
            + ((double)y2 * y2 + (double)y3 * y3);
    }
    block_reduce2(s, ss);
    if (publish_and_check_last(s, ss, part, counter)) {
        double ts = 0.0, tss = 0.0;
        for (int i = threadIdx.x; i < (int)gridDim.x; i += blockDim.x) {
            ts += part[2 * i]; tss += part[2 * i + 1];
        }
        block_reduce2(ts, tss);
        if (threadIdx.x == 0) {
            double dn   = (double)n;
            double mean = ts / dn;
            double var  = (tss - ts * ts / dn) / (dn - 1.0);
            double sc   = (1.0 / sqrt(var)) * (double)oscale[0];
            params[2] = (float)sc;
            params[3] = (float)(-mean * sc);
            __threadfence();
        }
    }
}

// Pass 3: out = y * params[2] + params[3]. Non-temporal stores keep `data`
// resident in L3 (data 128MB + out 128MB == L3 size; NT writes avoid evicting
// the read stream).
__global__ __launch_bounds__(THREADS) void k_final(
        const floatx4* __restrict__ in, floatx4* __restrict__ out,
        const float* __restrict__ params, int n4) {
    const float mean1  = params[0];
    const float scale1 = params[1];
    const float a      = params[2];
    const float b      = params[3];
    const int stride = gridDim.x * blockDim.x;
    for (int i = blockIdx.x * blockDim.x + threadIdx.x; i < n4; i += stride) {
        floatx4 v = in[i];
        floatx4 r;
        r.x = fmaf(transform(v.x, mean1, scale1), a, b);
        r.y = fmaf(transform(v.y, mean1, scale1), a, b);
        r.z = fmaf(transform(v.z, mean1, scale1), a, b);
        r.w = fmaf(transform(v.w, mean1, scale1), a, b);
        __builtin_nontemporal_store(r, &out[i]);
    }
}

extern "C" void kernel_launch(void* const* d_in, const int* in_sizes, int n_in,
                              void* d_out, int out_size, void* d_ws, size_t ws_size,
                              hipStream_t stream) {
    const float* data   = (const float*)d_in[0];
    const float* iscale = (const float*)d_in[1];
    const float* oscale = (const float*)d_in[2];
    // d_in[3] (weight) is mathematically irrelevant: softmax rows sum to 1,
    // so _integral(param, idx, sm) == param[idx].
    float* out = (float*)d_out;

    const int n  = in_sizes[0];      // 33554432 = 2^25, divisible by 4
    const int n4 = n / 4;

    // Workspace layout.
    double*   part1    = (double*)d_ws;                          // 2048*2 doubles
    double*   part2    = (double*)((char*)d_ws + 32 * 1024);     // 2048*2 doubles
    float*    params   = (float*)((char*)d_ws + 64 * 1024);      // 4 floats
    unsigned* counters = (unsigned*)((char*)d_ws + 64 * 1024 + 64); // 2 uints

    // Counters must be zero at the start of every (graph-replayed) call.
    (void)hipMemsetAsync(counters, 0, 2 * sizeof(unsigned), stream);

    k_stats1<<<BLOCKS, THREADS, 0, stream>>>((const floatx4*)data, part1, params,
                                             iscale, counters + 0, n4, n);
    k_stats2<<<BLOCKS, THREADS, 0, stream>>>((const floatx4*)data, part2, params,
                                             oscale, counters + 1, n4, n);
    k_final <<<BLOCKS, THREADS, 0, stream>>>((const floatx4*)data, (floatx4*)out,
                                             params, n4);
}

// Round 4
// 108.641 us; speedup vs baseline: 1.9341x; 1.9341x over previous
//
#include <hip/hip_runtime.h>
#include <math.h>

#define BLOCKS  2048
#define THREADS 256

// Native clang vector type: works with __builtin_nontemporal_store
// (HIP's float4 class type does not).
typedef float floatx4 __attribute__((ext_vector_type(4)));

// ---------------------------------------------------------------------------
// Fused pointwise transform (everything between the two normalizations).
//   theta = -pi + 2*pi*sigmoid(x)     (exact closed form of the linspace lerp)
//   ds    = 3 * |tanh(x)|             (exact closed form of the linspace lerp)
//   y     = x * exp(ds*sin(theta)) + ds*cos(theta)
// Trans-op-minimal: ~5 transcendental ops (v_exp x2, v_sin, v_cos via
// revolutions, v_rcp x2), ~15 VALU ops.
// ---------------------------------------------------------------------------
__device__ __forceinline__ float transform(float d, float mean1, float scale1) {
    float x  = (d - mean1) * scale1;              // scale1 = iscale / std1
    float ax = fabsf(x);
    float w  = __expf(-ax);                       // e^{-|x|}  in (0,1]
    float r  = __builtin_amdgcn_rcpf(1.0f + w);   // sigma(|x|) = 1/(1+w)
    float sg = (x >= 0.0f) ? r : (1.0f - r);      // sigmoid(x)
    float u  = w * w;                             // e^{-2|x|}
    float th = (1.0f - u) * __builtin_amdgcn_rcpf(1.0f + u);  // |tanh(x)|
    float ds = 3.0f * th;
    float rev = sg - 0.5f;                        // theta / (2*pi) in (-0.5,0.5)
    float sn = __builtin_amdgcn_sinf(rev);        // sin(theta) (hw: revolutions)
    float cs = __builtin_amdgcn_cosf(rev);        // cos(theta)
    return fmaf(x, __expf(ds * sn), ds * cs);     // x*exp(dy) + dx
}

// Block-level {sum, sumsq} reduction in double. Result valid in thread 0.
__device__ __forceinline__ void block_reduce2(double& s, double& ss) {
    for (int o = 32; o > 0; o >>= 1) {
        s  += __shfl_down(s,  o);
        ss += __shfl_down(ss, o);
    }
    __shared__ double ls[4], lss[4];
    const int wave = threadIdx.x >> 6;
    const int lane = threadIdx.x & 63;
    if (lane == 0) { ls[wave] = s; lss[wave] = ss; }
    __syncthreads();
    if (threadIdx.x == 0) {
        s = ls[0]; ss = lss[0];
        #pragma unroll
        for (int w = 1; w < THREADS / 64; ++w) { s += ls[w]; ss += lss[w]; }
    }
}

__device__ __forceinline__ void acc4(double& s, double& ss, floatx4 v) {
    s  += ((double)v.x + (double)v.y) + ((double)v.z + (double)v.w);
    ss += ((double)v.x * v.x + (double)v.y * v.y)
        + ((double)v.z * v.z + (double)v.w * v.w);
}

// Pass 1: per-block partial {sum, sumsq} of raw data. 4-way unrolled
// grid-stride loop -> 4 independent dwordx4 loads in flight per thread.
__global__ __launch_bounds__(THREADS) void k_stats1(
        const floatx4* __restrict__ in, double* __restrict__ part, int n4) {
    double s = 0.0, ss = 0.0;
    const int stride = gridDim.x * blockDim.x;
    int i = blockIdx.x * blockDim.x + threadIdx.x;
    for (; i + 3 * stride < n4; i += 4 * stride) {
        floatx4 a = in[i];
        floatx4 b = in[i + stride];
        floatx4 c = in[i + 2 * stride];
        floatx4 d = in[i + 3 * stride];
        acc4(s, ss, a); acc4(s, ss, b); acc4(s, ss, c); acc4(s, ss, d);
    }
    for (; i < n4; i += stride) acc4(s, ss, in[i]);
    block_reduce2(s, ss);
    if (threadIdx.x == 0) {
        part[2 * blockIdx.x]     = s;
        part[2 * blockIdx.x + 1] = ss;
    }
}

// Finalize pass 1: params[0] = mean1, params[1] = iscale/std1 (ddof=1).
__global__ __launch_bounds__(THREADS) void k_fin1(
        const double* __restrict__ part, float* __restrict__ params,
        const float* __restrict__ iscale, int n) {
    double s = 0.0, ss = 0.0;
    for (int i = threadIdx.x; i < BLOCKS; i += blockDim.x) {
        s += part[2 * i]; ss += part[2 * i + 1];
    }
    block_reduce2(s, ss);
    if (threadIdx.x == 0) {
        double dn   = (double)n;
        double mean = s / dn;
        double var  = (ss - s * s / dn) / (dn - 1.0);
        params[0] = (float)mean;
        params[1] = (float)((1.0 / sqrt(var)) * (double)iscale[0]);
    }
}

// Pass 2: per-block partial {sum, sumsq} of transformed y (recomputed).
__global__ __launch_bounds__(THREADS) void k_stats2(
        const floatx4* __restrict__ in, double* __restrict__ part,
        const float* __restrict__ params, int n4) {
    const float mean1  = params[0];
    const float scale1 = params[1];
    double s = 0.0, ss = 0.0;
    const int stride = gridDim.x * blockDim.x;
    int i = blockIdx.x * blockDim.x + threadIdx.x;
    for (; i + 3 * stride < n4; i += 4 * stride) {
        floatx4 vv[4];
        vv[0] = in[i];
        vv[1] = in[i + stride];
        vv[2] = in[i + 2 * stride];
        vv[3] = in[i + 3 * stride];
        #pragma unroll
        for (int k = 0; k < 4; ++k) {
            floatx4 y;
            y.x = transform(vv[k].x, mean1, scale1);
            y.y = transform(vv[k].y, mean1, scale1);
            y.z = transform(vv[k].z, mean1, scale1);
            y.w = transform(vv[k].w, mean1, scale1);
            acc4(s, ss, y);
        }
    }
    for (; i < n4; i += stride) {
        floatx4 v = in[i], y;
        y.x = transform(v.x, mean1, scale1);
        y.y = transform(v.y, mean1, scale1);
        y.z = transform(v.z, mean1, scale1);
        y.w = transform(v.w, mean1, scale1);
        acc4(s, ss, y);
    }
    block_reduce2(s, ss);
    if (threadIdx.x == 0) {
        part[2 * blockIdx.x]     = s;
        part[2 * blockIdx.x + 1] = ss;
    }
}

// Finalize pass 2: params[2] = oscale/std2, params[3] = -mean2 * params[2].
__global__ __launch_bounds__(THREADS) void k_fin2(
        const double* __restrict__ part, float* __restrict__ params,
        const float* __restrict__ oscale, int n) {
    double s = 0.0, ss = 0.0;
    for (int i = threadIdx.x; i < BLOCKS; i += blockDim.x) {
        s += part[2 * i]; ss += part[2 * i + 1];
    }
    block_reduce2(s, ss);
    if (threadIdx.x == 0) {
        double dn   = (double)n;
        double mean = s / dn;
        double var  = (ss - s * s / dn) / (dn - 1.0);
        double sc   = (1.0 / sqrt(var)) * (double)oscale[0];
        params[2] = (float)sc;
        params[3] = (float)(-mean * sc);
    }
}

// Pass 3: out = y * params[2] + params[3]. NT stores keep `data` resident in
// L3 (data 128MB + out 128MB == L3 size; NT writes avoid evicting the reads).
__global__ __launch_bounds__(THREADS) void k_final(
        const floatx4* __restrict__ in, floatx4* __restrict__ out,
        const float* __restrict__ params, int n4) {
    const float mean1  = params[0];
    const float scale1 = params[1];
    const float a      = params[2];
    const float b      = params[3];
    const int stride = gridDim.x * blockDim.x;
    int i = blockIdx.x * blockDim.x + threadIdx.x;
    for (; i + stride < n4; i += 2 * stride) {
        floatx4 v0 = in[i];
        floatx4 v1 = in[i + stride];
        floatx4 r0, r1;
        r0.x = fmaf(transform(v0.x, mean1, scale1), a, b);
        r0.y = fmaf(transform(v0.y, mean1, scale1), a, b);
        r0.z = fmaf(transform(v0.z, mean1, scale1), a, b);
        r0.w = fmaf(transform(v0.w, mean1, scale1), a, b);
        r1.x = fmaf(transform(v1.x, mean1, scale1), a, b);
        r1.y = fmaf(transform(v1.y, mean1, scale1), a, b);
        r1.z = fmaf(transform(v1.z, mean1, scale1), a, b);
        r1.w = fmaf(transform(v1.w, mean1, scale1), a, b);
        __builtin_nontemporal_store(r0, &out[i]);
        __builtin_nontemporal_store(r1, &out[i + stride]);
    }
    for (; i < n4; i += stride) {
        floatx4 v = in[i], r;
        r.x = fmaf(transform(v.x, mean1, scale1), a, b);
        r.y = fmaf(transform(v.y, mean1, scale1), a, b);
        r.z = fmaf(transform(v.z, mean1, scale1), a, b);
        r.w = fmaf(transform(v.w, mean1, scale1), a, b);
        __builtin_nontemporal_store(r, &out[i]);
    }
}

extern "C" void kernel_launch(void* const* d_in, const int* in_sizes, int n_in,
                              void* d_out, int out_size, void* d_ws, size_t ws_size,
                              hipStream_t stream) {
    const float* data   = (const float*)d_in[0];
    const float* iscale = (const float*)d_in[1];
    const float* oscale = (const float*)d_in[2];
    // d_in[3] (weight) is mathematically irrelevant: softmax rows sum to 1,
    // so _integral(param, idx, sm) == param[idx].
    float* out = (float*)d_out;

    const int n  = in_sizes[0];      // 33554432 = 2^25, divisible by 4
    const int n4 = n / 4;

    double* part   = (double*)d_ws;                                   // 2048*2 doubles
    float*  params = (float*)((char*)d_ws + BLOCKS * 2 * sizeof(double)); // 4 floats

    k_stats1<<<BLOCKS, THREADS, 0, stream>>>((const floatx4*)data, part, n4);
    k_fin1  <<<1,      THREADS, 0, stream>>>(part, params, iscale, n);
    k_stats2<<<BLOCKS, THREADS, 0, stream>>>((const floatx4*)data, part, params, n4);
    k_fin2  <<<1,      THREADS, 0, stream>>>(part, params, oscale, n);
    k_final <<<BLOCKS, THREADS, 0, stream>>>((const floatx4*)data, (floatx4*)out,
                                             params, n4);
}